// Round 8
// baseline (274.225 us; speedup 1.0000x reference)
//
#include <hip/hip_runtime.h>
#include <hip/hip_bf16.h>
#include <math.h>

#define DIM 768
#define NHEAD 12
#define HD 64
#define HIDDEN 384
#define BATCH 8
#define SEQ 1024
#define ROWS (BATCH*SEQ)
#define CHUNKB 4                 // batches per qkv/attn chunk (fallback path)
#define CHUNKR (CHUNKB*SEQ)

typedef short bf16x8 __attribute__((ext_vector_type(8)));
typedef short bf16x4 __attribute__((ext_vector_type(4)));
typedef float f32x4 __attribute__((ext_vector_type(4)));
typedef unsigned short u16;
typedef unsigned int u32;

__device__ __forceinline__ u16 f2bs(float f) {
    unsigned int u = __float_as_uint(f);
    unsigned int r = (u + 0x7FFFu + ((u >> 16) & 1u)) >> 16;
    return (u16)r;
}

// HW packed bf16 convert (v_cvt_pk_bf16_f32 on gfx950), RNE
__device__ __forceinline__ u32 packbf2(float a, float b) {
    __hip_bfloat162 h = __float22bfloat162_rn(make_float2(a, b));
    u32 r;
    __builtin_memcpy(&r, &h, 4);
    return r;
}

// async global->LDS DMA, 16 B/lane; LDS dest = wave-uniform base + lane*16
__device__ __forceinline__ void gld16(const u16* g, u16* l) {
    __builtin_amdgcn_global_load_lds(
        (const __attribute__((address_space(1))) unsigned int*)g,
        (__attribute__((address_space(3))) unsigned int*)l, 16, 0, 0);
}

// ---------------- fused tiled weight transpose: Wt[n][k] = bf16(W[k][n]) ----------------
// All four weight matrices in ONE launch. 2880 32x32 tiles:
//   [0,1728) wqkv | [1728,2304) wproj | [2304,2592) wfc1 | [2592,2880) wfc2
__global__ __launch_bounds__(256) void wtrans4(const float* __restrict__ W0, u16* __restrict__ T0,
                                               const float* __restrict__ W1, u16* __restrict__ T1,
                                               const float* __restrict__ W2, u16* __restrict__ T2,
                                               const float* __restrict__ W3, u16* __restrict__ T3) {
    __shared__ float tile[32][33];
    int id = blockIdx.x;
    const float* W; u16* T; int K, N, nt;
    if (id < 1728)      {            W = W0; T = T0; K = 768; N = 2304; nt = 72; }
    else if (id < 2304) { id -= 1728; W = W1; T = T1; K = 768; N = 768;  nt = 24; }
    else if (id < 2592) { id -= 2304; W = W2; T = T2; K = 768; N = 384;  nt = 12; }
    else                { id -= 2592; W = W3; T = T3; K = 384; N = 768;  nt = 24; }
    int n0 = (id % nt) * 32, k0 = (id / nt) * 32;
    int tx = threadIdx.x & 31, ty = threadIdx.x >> 5;
#pragma unroll
    for (int i = 0; i < 4; i++)
        tile[ty + i * 8][tx] = W[(long)(k0 + ty + i * 8) * N + n0 + tx];
    __syncthreads();
#pragma unroll
    for (int i = 0; i < 4; i++)
        T[(long)(n0 + ty + i * 8) * K + k0 + tx] = f2bs(tile[tx][ty + i * 8]);
}

// ---------------- layernorm: fp32 in -> bf16 out, one block per row ----------------
__global__ __launch_bounds__(256) void lnorm(const float* __restrict__ X,
                                             const float* __restrict__ w,
                                             const float* __restrict__ b,
                                             u16* __restrict__ Y) {
    int row = blockIdx.x;
    const float* xr = X + (long)row * DIM;
    int t = threadIdx.x;
    float v0 = xr[t], v1 = xr[t + 256], v2 = xr[t + 512];
    float s = v0 + v1 + v2;
    float s2 = v0 * v0 + v1 * v1 + v2 * v2;
    for (int off = 1; off < 64; off <<= 1) {
        s  += __shfl_xor(s,  off, 64);
        s2 += __shfl_xor(s2, off, 64);
    }
    __shared__ float ss[4], ss2[4];
    int wid = t >> 6;
    if ((t & 63) == 0) { ss[wid] = s; ss2[wid] = s2; }
    __syncthreads();
    s  = ss[0] + ss[1] + ss[2] + ss[3];
    s2 = ss2[0] + ss2[1] + ss2[2] + ss2[3];
    float mu = s * (1.0f / DIM);
    float var = s2 * (1.0f / DIM) - mu * mu;
    float rstd = rsqrtf(var + 1e-5f);
    u16* yr = Y + (long)row * DIM;
    yr[t]       = f2bs((v0 - mu) * rstd * w[t]       + b[t]);
    yr[t + 256] = f2bs((v1 - mu) * rstd * w[t + 256] + b[t + 256]);
    yr[t + 512] = f2bs((v2 - mu) * rstd * w[t + 512] + b[t + 512]);
}

// ---------------- bf16 MFMA GEMM, C = A[M,K] @ Bt[N,K]^T, BMxBNx64 tiles ----------------
// Staging via global_load_lds width=16 into unpadded stride-64 LDS with XOR swizzle:
// LDS[row][c] holds global chunk (c ^ (row&7)); fragment reads re-apply the XOR.
// EPI: 0 = bf16 out; 1 = f32 out + resid; 2 = bf16 out + bias + exact GELU; 3 = f32 out + resid + bias
template <int BM, int BN, int EPI>
__global__ __launch_bounds__(256) void gemm_bt(const u16* __restrict__ A,
                                               const u16* __restrict__ Bt,
                                               int M, int N, int K,
                                               u16* __restrict__ Cb,
                                               float* __restrict__ Cf,
                                               const float* __restrict__ resid,
                                               const float* __restrict__ bias) {
    constexpr int MB = BM / 32, NB = BN / 32;
    __shared__ u16 As[BM * 64];
    __shared__ u16 Bs[BN * 64];
    int m0 = blockIdx.y * BM;
    int n0 = blockIdx.x * BN;
    int t = threadIdx.x;
    int lane = t & 63, w = t >> 6;
    int quad = lane >> 4, l16 = lane & 15;
    int wr = w >> 1, wc = w & 1;
    int lr = lane >> 3, lc = lane & 7;
    int sc = (lc ^ lr) * 8;      // swizzled source chunk offset (u16 units)
    int x7 = l16 & 7;            // row&7 for fragment reads

    f32x4 acc[MB][NB];
#pragma unroll
    for (int mb = 0; mb < MB; mb++)
#pragma unroll
        for (int nb = 0; nb < NB; nb++) acc[mb][nb] = (f32x4){0.f, 0.f, 0.f, 0.f};

    for (int kt = 0; kt < K; kt += 64) {
        __syncthreads();
#pragma unroll
        for (int i = 0; i < BM / 32; i++) {
            int rb = i * 32 + w * 8;
            gld16(&A[(long)(m0 + rb + lr) * K + kt + sc], &As[rb * 64]);
        }
#pragma unroll
        for (int i = 0; i < BN / 32; i++) {
            int rb = i * 32 + w * 8;
            gld16(&Bt[(long)(n0 + rb + lr) * K + kt + sc], &Bs[rb * 64]);
        }
        __syncthreads();
#pragma unroll
        for (int kh = 0; kh < 2; kh++) {
            bf16x8 af[MB], bfr[NB];
#pragma unroll
            for (int mb = 0; mb < MB; mb++)
                af[mb] = *(const bf16x8*)&As[(wr * (BM / 2) + mb * 16 + l16) * 64 +
                                             (((kh * 4 + quad) ^ x7) * 8)];
#pragma unroll
            for (int nb = 0; nb < NB; nb++)
                bfr[nb] = *(const bf16x8*)&Bs[(wc * (BN / 2) + nb * 16 + l16) * 64 +
                                              (((kh * 4 + quad) ^ x7) * 8)];
#pragma unroll
            for (int mb = 0; mb < MB; mb++)
#pragma unroll
                for (int nb = 0; nb < NB; nb++)
                    acc[mb][nb] = __builtin_amdgcn_mfma_f32_16x16x32_bf16(af[mb], bfr[nb], acc[mb][nb], 0, 0, 0);
        }
    }

    int mbase = m0 + wr * (BM / 2), nbase = n0 + wc * (BN / 2);
#pragma unroll
    for (int mb = 0; mb < MB; mb++)
#pragma unroll
        for (int nb = 0; nb < NB; nb++) {
            int r0 = mbase + mb * 16 + quad * 4;
            int c = nbase + nb * 16 + l16;
#pragma unroll
            for (int r = 0; r < 4; r++) {
                float v = acc[mb][nb][r];
                long idx = (long)(r0 + r) * N + c;
                if (EPI == 0) {
                    Cb[idx] = f2bs(v);
                } else if (EPI == 1) {
                    Cf[idx] = resid[idx] + v;
                } else if (EPI == 2) {
                    float xg = v + bias[c];
                    Cb[idx] = f2bs(xg * 0.5f * (1.0f + erff(xg * 0.70710678118f)));
                } else {
                    Cf[idx] = resid[idx] + v + bias[c];
                }
            }
        }
}

// ---------------- flash attention: QT=128 q-rows/block (8 waves), KT=64 keys/tile ----------------
// Per wave: 16 q-rows; S^T QK^T, in-lane softmax, in-register P.
// PV via 16x16x32 MFMA with PERMUTED contraction index: MFMA sums over k in any order,
// so sigma(quad*8+j) = {jb0*16+quad*4+j (j<4); jb1*16+quad*4+j-4 (j>=4)} lets the
// K=32 A-fragment be the concat of two in-lane P quads (s[jb0],s[jb1]) and the
// B-fragment the concat of the two existing bf16x4 V reads -- same data, HALF the
// MFMA instructions (8 vs 16) and the o[dt] dependent chain 4 -> 2.
// K staged via global_load_lds DMA; V via register prefetch + pack into Vs[d][kv] s72.
// Double-buffered, one barrier per tile. defer-max THR=8 (T13).
__global__ __launch_bounds__(512, 6) void attn(const u16* __restrict__ QKV, u16* __restrict__ O) {
    __shared__ u16 Ks[2][64 * 64];    // [buf][kv][chunk-swizzled d]  (DMA-staged)
    __shared__ u16 Vs[2][64 * 72];    // [buf][d][kv], stride 72      (reg-packed)
    int lin = blockIdx.x;
    int cpx = gridDim.x >> 3;                 // gridDim.x divisible by 8
    int l = (lin & 7) * cpx + (lin >> 3);     // XCD-chunked bijection
    int q0 = (l & 7) * 128;                   // SEQ/128 = 8 q-chunks
    int hb = l >> 3;
    int h = hb % NHEAD;
    int b = hb / NHEAD;
    int t = threadIdx.x;
    int lane = t & 63, w = t >> 6;            // w in 0..7
    int quad = lane >> 4, l16 = lane & 15;
    int x7 = l16 & 7;

    const long rs = 3 * DIM;  // 2304
    const u16* base = QKV + (long)b * SEQ * rs;

    // Q fragments: wave w owns rows q0 + w*16 .. +15
    bf16x8 qf0, qf1;
    {
        int qrow = q0 + w * 16 + l16;
        qf0 = *(const bf16x8*)&base[(long)qrow * rs + h * 64 + quad * 8];
        qf1 = *(const bf16x8*)&base[(long)qrow * rs + h * 64 + 32 + quad * 8];
    }

    f32x4 o[4];
#pragma unroll
    for (int dt = 0; dt < 4; dt++) o[dt] = (f32x4){0.f, 0.f, 0.f, 0.f};
    float m_run = -1e30f;
    float l_run = 0.f;
    const float L2E8 = 11.54156032f;  // 8 * log2(e)

    // ---- staging sources ----
    // K DMA: wave w stages rows w*8..+7 in ONE gld16 (8 lanes/row, 16B chunks,
    //        source chunk pre-swizzled (lc ^ lr); row&7 == lr since w*8 is 8-aligned).
    int lr = lane >> 3, lc = lane & 7;
    int sc = (lc ^ lr) * 8;
    const u16* kA = &base[(long)(w * 8 + lr) * rs + DIM + h * 64 + sc];
    // V regs: thread t loads V rows 2vc,2vc+1 (vc=t&31), d-group vo*4..+3 (vo=t>>5, 0..15)
    int vc = t & 31, vo = t >> 5;
    const u16* vptr = &base[(long)(2 * vc) * rs + 2 * DIM + h * 64 + vo * 4];
    const long kstep = (long)64 * rs;

    bf16x4 vp0, vp1;
    // ---- prologue: tile 0 ----
    gld16(kA, &Ks[0][(w * 8) * 64]);
    kA += kstep;
    vp0 = *(const bf16x4*)&vptr[0];
    vp1 = *(const bf16x4*)&vptr[rs];
    vptr += kstep;
#pragma unroll
    for (int j = 0; j < 4; j++) {
        u32 pk = (u32)(u16)vp0[j] | ((u32)(u16)vp1[j] << 16);
        *(u32*)&Vs[0][(vo * 4 + j) * 72 + 2 * vc] = pk;
    }
    // V regs for tile 1
    vp0 = *(const bf16x4*)&vptr[0];
    vp1 = *(const bf16x4*)&vptr[rs];
    vptr += kstep;
    __syncthreads();   // drains K DMA (vmcnt) + V ds_writes (lgkm) before reads

    for (int it = 0; it < SEQ / 64; it++) {
        int cur = it & 1;
        if (it < SEQ / 64 - 1) {
            int nb = cur ^ 1;
            // K DMA for tile it+1 (buf nb fully read in iter it-1; barrier passed)
            gld16(kA, &Ks[nb][(w * 8) * 64]);
            kA += kstep;
            // V write for tile it+1 (regs loaded one iteration ago)
#pragma unroll
            for (int j = 0; j < 4; j++) {
                u32 pk = (u32)(u16)vp0[j] | ((u32)(u16)vp1[j] << 16);
                *(u32*)&Vs[nb][(vo * 4 + j) * 72 + 2 * vc] = pk;
            }
            if (it < SEQ / 64 - 2) {
                vp0 = *(const bf16x4*)&vptr[0];
                vp1 = *(const bf16x4*)&vptr[rs];
                vptr += kstep;
            }
        }

        // ---- QK^T from buf[cur]: lane (quad,l16) gets s[jb][r] = S[q=l16][kv=jb*16+quad*4+r]
        f32x4 s[4];
#pragma unroll
        for (int jb = 0; jb < 4; jb++) {
            int row = jb * 16 + l16;
            bf16x8 kf0 = *(const bf16x8*)&Ks[cur][row * 64 + ((quad ^ x7) * 8)];
            bf16x8 kf1 = *(const bf16x8*)&Ks[cur][row * 64 + (((4 + quad) ^ x7) * 8)];
            f32x4 z = (f32x4){0.f, 0.f, 0.f, 0.f};
            z = __builtin_amdgcn_mfma_f32_16x16x32_bf16(kf0, qf0, z, 0, 0, 0);
            z = __builtin_amdgcn_mfma_f32_16x16x32_bf16(kf1, qf1, z, 0, 0, 0);
            s[jb] = z;
        }

        // ---- softmax (vectorized)
        f32x4 mx = __builtin_elementwise_max(__builtin_elementwise_max(s[0], s[1]),
                                             __builtin_elementwise_max(s[2], s[3]));
        float m1 = fmaxf(fmaxf(mx[0], mx[1]), fmaxf(mx[2], mx[3]));
        m1 = fmaxf(m1, __shfl_xor(m1, 16, 64));
        m1 = fmaxf(m1, __shfl_xor(m1, 32, 64));

        // defer-max (T13, THR=8): skip O/l rescale unless some row's max grew by >8
        // (P then bounded by e^8 ~ 2981 -- safe in f32 sums / bf16 P).
        float mn = m_run;
        int resc = __any(m1 > mn + 8.0f);
        if (resc) mn = fmaxf(mn, m1);
        float mn8 = mn * L2E8;
        f32x4 cmul = {L2E8, L2E8, L2E8, L2E8};
        f32x4 cadd = {-mn8, -mn8, -mn8, -mn8};
#pragma unroll
        for (int jb = 0; jb < 4; jb++) {
            f32x4 e = s[jb] * cmul + cadd;
            e[0] = exp2f(e[0]); e[1] = exp2f(e[1]);
            e[2] = exp2f(e[2]); e[3] = exp2f(e[3]);
            s[jb] = e;
        }
        f32x4 sv = (s[0] + s[1]) + (s[2] + s[3]);
        float rsum = (sv[0] + sv[1]) + (sv[2] + sv[3]);
        rsum += __shfl_xor(rsum, 16, 64);
        rsum += __shfl_xor(rsum, 32, 64);

        if (resc) {
            float alpha = exp2f((m_run - mn) * L2E8);
            m_run = mn;
            float a0 = __shfl(alpha, quad * 4 + 0, 16);
            float a1 = __shfl(alpha, quad * 4 + 1, 16);
            float a2 = __shfl(alpha, quad * 4 + 2, 16);
            float a3 = __shfl(alpha, quad * 4 + 3, 16);
#pragma unroll
            for (int dt = 0; dt < 4; dt++) {
                o[dt][0] *= a0; o[dt][1] *= a1;
                o[dt][2] *= a2; o[dt][3] *= a3;
            }
            l_run = l_run * alpha + rsum;
        } else {
            l_run += rsum;
        }

        // ---- PV: 16x16x32 with permuted k (see header). A = concat(P[jb0],P[jb1]) in-lane;
        //          B = concat of the two bf16x4 V^T reads (same addresses as K=16 version).
#pragma unroll
        for (int jp = 0; jp < 2; jp++) {
            int jb0 = 2 * jp, jb1 = 2 * jp + 1;
            union { u32 u[4]; bf16x8 v; } pa;
            pa.u[0] = packbf2(s[jb0][0], s[jb0][1]);
            pa.u[1] = packbf2(s[jb0][2], s[jb0][3]);
            pa.u[2] = packbf2(s[jb1][0], s[jb1][1]);
            pa.u[3] = packbf2(s[jb1][2], s[jb1][3]);
#pragma unroll
            for (int dt = 0; dt < 4; dt++) {
                union { bf16x4 h[2]; bf16x8 v; } vb;
                vb.h[0] = *(const bf16x4*)&Vs[cur][(dt * 16 + l16) * 72 + jb0 * 16 + quad * 4];
                vb.h[1] = *(const bf16x4*)&Vs[cur][(dt * 16 + l16) * 72 + jb1 * 16 + quad * 4];
                o[dt] = __builtin_amdgcn_mfma_f32_16x16x32_bf16(pa.v, vb.v, o[dt], 0, 0, 0);
            }
        }

        if (it < SEQ / 64 - 1) __syncthreads();   // protects buf[cur] overwrite next iter
    }

    // epilogue: rows quad*4+r, cols dt*16+l16
    {
        float l0 = __shfl(l_run, quad * 4 + 0, 16);
        float l1 = __shfl(l_run, quad * 4 + 1, 16);
        float l2 = __shfl(l_run, quad * 4 + 2, 16);
        float l3 = __shfl(l_run, quad * 4 + 3, 16);
        u16* orow = O + ((long)(b * SEQ + q0 + w * 16)) * DIM + h * 64;
#pragma unroll
        for (int dt = 0; dt < 4; dt++) {
            u32 p01 = packbf2(o[dt][0] / l0, o[dt][1] / l1);
            u32 p23 = packbf2(o[dt][2] / l2, o[dt][3] / l3);
            int cidx = dt * 16 + l16;
            orow[(long)(quad * 4 + 0) * DIM + cidx] = (u16)p01;
            orow[(long)(quad * 4 + 1) * DIM + cidx] = (u16)(p01 >> 16);
            orow[(long)(quad * 4 + 2) * DIM + cidx] = (u16)p23;
            orow[(long)(quad * 4 + 3) * DIM + cidx] = (u16)(p23 >> 16);
        }
    }
}

extern "C" void kernel_launch(void* const* d_in, const int* in_sizes, int n_in,
                              void* d_out, int out_size, void* d_ws, size_t ws_size,
                              hipStream_t stream) {
    const float* x     = (const float*)d_in[0];
    const float* ln1w  = (const float*)d_in[1];
    const float* ln1b  = (const float*)d_in[2];
    const float* ln2w  = (const float*)d_in[3];
    const float* ln2b  = (const float*)d_in[4];
    const float* wqkv  = (const float*)d_in[5];
    const float* wproj = (const float*)d_in[6];
    const float* wfc1  = (const float*)d_in[7];
    const float* bfc1  = (const float*)d_in[8];
    const float* wfc2  = (const float*)d_in[9];
    const float* bfc2  = (const float*)d_in[10];
    float* out = (float*)d_out;

    char* ws = (char*)d_ws;
    size_t off = 0;
    auto alloc = [&](size_t bytes) {
        void* p = ws + off;
        off = (off + bytes + 255) & ~(size_t)255;
        return p;
    };
    u16* wt_qkv  = (u16*)alloc((size_t)3 * DIM * DIM * 2);
    u16* wt_proj = (u16*)alloc((size_t)DIM * DIM * 2);
    u16* wt_fc1  = (u16*)alloc((size_t)HIDDEN * DIM * 2);
    u16* wt_fc2  = (u16*)alloc((size_t)DIM * HIDDEN * 2);
    u16* hbuf    = (u16*)alloc((size_t)ROWS * DIM * 2);      // ln1 out -> attn out -> ln2 out
    u16* gbuf    = (u16*)alloc((size_t)ROWS * HIDDEN * 2);   // gelu out
    size_t qkv_bytes = (size_t)ROWS * 3 * DIM * 2;           // 37.75 MB
    u16* qkvfull = (off + qkv_bytes + 1024 <= ws_size) ? (u16*)alloc(qkv_bytes) : nullptr;

    // 1. weights -> bf16 transposed (single fused launch)
    wtrans4<<<2880, 256, 0, stream>>>(wqkv, wt_qkv, wproj, wt_proj,
                                      wfc1, wt_fc1, wfc2, wt_fc2);

    // 2. ln1
    lnorm<<<ROWS, 256, 0, stream>>>(x, ln1w, ln1b, hbuf);

    // 3. qkv + attention
    if (qkvfull) {
        gemm_bt<128, 128, 0><<<dim3(3 * DIM / 128, ROWS / 128), 256, 0, stream>>>(
            hbuf, wt_qkv, ROWS, 3 * DIM, DIM, qkvfull, nullptr, nullptr, nullptr);
        attn<<<(SEQ / 128) * NHEAD * BATCH, 512, 0, stream>>>(qkvfull, hbuf);
    } else {
        u16* qd = (u16*)d_out;
        for (int c = 0; c < ROWS / CHUNKR; c++) {
            const u16* hA = hbuf + (size_t)c * CHUNKR * DIM;
            gemm_bt<128, 128, 0><<<dim3(3 * DIM / 128, CHUNKR / 128), 256, 0, stream>>>(
                hA, wt_qkv, CHUNKR, 3 * DIM, DIM, qd, nullptr, nullptr, nullptr);
            attn<<<(SEQ / 128) * NHEAD * CHUNKB, 512, 0, stream>>>(
                qd, hbuf + (size_t)c * CHUNKR * DIM);
        }
    }

    // 4. x1 = x + attn_out @ w_proj  (fp32 into d_out)
    gemm_bt<128, 64, 1><<<dim3(DIM / 64, ROWS / 128), 256, 0, stream>>>(
        hbuf, wt_proj, ROWS, DIM, DIM, nullptr, out, x, nullptr);

    // 5. ln2
    lnorm<<<ROWS, 256, 0, stream>>>(out, ln2w, ln2b, hbuf);

    // 6. g = gelu(hbuf @ w_fc1 + b_fc1)  (128-row tile: 64x64 is the slow tile class)
    gemm_bt<128, 64, 2><<<dim3(HIDDEN / 64, ROWS / 128), 256, 0, stream>>>(
        hbuf, wt_fc1, ROWS, HIDDEN, DIM, gbuf, nullptr, nullptr, bfc1);

    // 7. out = x1 + g @ w_fc2 + b_fc2  (fp32, in-place over x1)
    gemm_bt<128, 64, 3><<<dim3(DIM / 64, ROWS / 128), 256, 0, stream>>>(
        gbuf, wt_fc2, ROWS, DIM, HIDDEN, nullptr, out, out, bfc2);
}

// Round 9
// 258.929 us; speedup vs baseline: 1.0591x; 1.0591x over previous
//
#include <hip/hip_runtime.h>
#include <hip/hip_bf16.h>
#include <math.h>

#define DIM 768
#define NHEAD 12
#define HD 64
#define HIDDEN 384
#define BATCH 8
#define SEQ 1024
#define ROWS (BATCH*SEQ)
#define CHUNKB 4                 // batches per qkv/attn chunk (fallback path)
#define CHUNKR (CHUNKB*SEQ)

typedef short bf16x8 __attribute__((ext_vector_type(8)));
typedef short bf16x4 __attribute__((ext_vector_type(4)));
typedef float f32x4 __attribute__((ext_vector_type(4)));
typedef unsigned short u16;
typedef unsigned int u32;

__device__ __forceinline__ u16 f2bs(float f) {
    unsigned int u = __float_as_uint(f);
    unsigned int r = (u + 0x7FFFu + ((u >> 16) & 1u)) >> 16;
    return (u16)r;
}

// HW packed bf16 convert (v_cvt_pk_bf16_f32 on gfx950), RNE
__device__ __forceinline__ u32 packbf2(float a, float b) {
    __hip_bfloat162 h = __float22bfloat162_rn(make_float2(a, b));
    u32 r;
    __builtin_memcpy(&r, &h, 4);
    return r;
}

// raw v_exp_f32 (1 instr): exp2f() lowers to the OCML range-checked libcall (~8 instr).
// Safe here: args are finite, <= 0; v_exp flushes large-negative to 0, ~1 ulp accuracy.
__device__ __forceinline__ float fexp2(float x) {
    return __builtin_amdgcn_exp2f(x);
}

// async global->LDS DMA, 16 B/lane; LDS dest = wave-uniform base + lane*16
__device__ __forceinline__ void gld16(const u16* g, u16* l) {
    __builtin_amdgcn_global_load_lds(
        (const __attribute__((address_space(1))) unsigned int*)g,
        (__attribute__((address_space(3))) unsigned int*)l, 16, 0, 0);
}

// ---------------- fused tiled weight transpose: Wt[n][k] = bf16(W[k][n]) ----------------
// All four weight matrices in ONE launch. 2880 32x32 tiles:
//   [0,1728) wqkv | [1728,2304) wproj | [2304,2592) wfc1 | [2592,2880) wfc2
__global__ __launch_bounds__(256) void wtrans4(const float* __restrict__ W0, u16* __restrict__ T0,
                                               const float* __restrict__ W1, u16* __restrict__ T1,
                                               const float* __restrict__ W2, u16* __restrict__ T2,
                                               const float* __restrict__ W3, u16* __restrict__ T3) {
    __shared__ float tile[32][33];
    int id = blockIdx.x;
    const float* W; u16* T; int K, N, nt;
    if (id < 1728)      {            W = W0; T = T0; K = 768; N = 2304; nt = 72; }
    else if (id < 2304) { id -= 1728; W = W1; T = T1; K = 768; N = 768;  nt = 24; }
    else if (id < 2592) { id -= 2304; W = W2; T = T2; K = 768; N = 384;  nt = 12; }
    else                { id -= 2592; W = W3; T = T3; K = 384; N = 768;  nt = 24; }
    int n0 = (id % nt) * 32, k0 = (id / nt) * 32;
    int tx = threadIdx.x & 31, ty = threadIdx.x >> 5;
#pragma unroll
    for (int i = 0; i < 4; i++)
        tile[ty + i * 8][tx] = W[(long)(k0 + ty + i * 8) * N + n0 + tx];
    __syncthreads();
#pragma unroll
    for (int i = 0; i < 4; i++)
        T[(long)(n0 + ty + i * 8) * K + k0 + tx] = f2bs(tile[tx][ty + i * 8]);
}

// ---------------- layernorm: fp32 in -> bf16 out, one block per row ----------------
__global__ __launch_bounds__(256) void lnorm(const float* __restrict__ X,
                                             const float* __restrict__ w,
                                             const float* __restrict__ b,
                                             u16* __restrict__ Y) {
    int row = blockIdx.x;
    const float* xr = X + (long)row * DIM;
    int t = threadIdx.x;
    float v0 = xr[t], v1 = xr[t + 256], v2 = xr[t + 512];
    float s = v0 + v1 + v2;
    float s2 = v0 * v0 + v1 * v1 + v2 * v2;
    for (int off = 1; off < 64; off <<= 1) {
        s  += __shfl_xor(s,  off, 64);
        s2 += __shfl_xor(s2, off, 64);
    }
    __shared__ float ss[4], ss2[4];
    int wid = t >> 6;
    if ((t & 63) == 0) { ss[wid] = s; ss2[wid] = s2; }
    __syncthreads();
    s  = ss[0] + ss[1] + ss[2] + ss[3];
    s2 = ss2[0] + ss2[1] + ss2[2] + ss2[3];
    float mu = s * (1.0f / DIM);
    float var = s2 * (1.0f / DIM) - mu * mu;
    float rstd = rsqrtf(var + 1e-5f);
    u16* yr = Y + (long)row * DIM;
    yr[t]       = f2bs((v0 - mu) * rstd * w[t]       + b[t]);
    yr[t + 256] = f2bs((v1 - mu) * rstd * w[t + 256] + b[t + 256]);
    yr[t + 512] = f2bs((v2 - mu) * rstd * w[t + 512] + b[t + 512]);
}

// ---------------- bf16 MFMA GEMM, C = A[M,K] @ Bt[N,K]^T, BMxBNx64 tiles ----------------
// Staging via global_load_lds width=16 into unpadded stride-64 LDS with XOR swizzle:
// LDS[row][c] holds global chunk (c ^ (row&7)); fragment reads re-apply the XOR.
// EPI: 0 = bf16 out; 1 = f32 out + resid; 2 = bf16 out + bias + exact GELU; 3 = f32 out + resid + bias
template <int BM, int BN, int EPI>
__global__ __launch_bounds__(256) void gemm_bt(const u16* __restrict__ A,
                                               const u16* __restrict__ Bt,
                                               int M, int N, int K,
                                               u16* __restrict__ Cb,
                                               float* __restrict__ Cf,
                                               const float* __restrict__ resid,
                                               const float* __restrict__ bias) {
    constexpr int MB = BM / 32, NB = BN / 32;
    __shared__ u16 As[BM * 64];
    __shared__ u16 Bs[BN * 64];
    int m0 = blockIdx.y * BM;
    int n0 = blockIdx.x * BN;
    int t = threadIdx.x;
    int lane = t & 63, w = t >> 6;
    int quad = lane >> 4, l16 = lane & 15;
    int wr = w >> 1, wc = w & 1;
    int lr = lane >> 3, lc = lane & 7;
    int sc = (lc ^ lr) * 8;      // swizzled source chunk offset (u16 units)
    int x7 = l16 & 7;            // row&7 for fragment reads

    f32x4 acc[MB][NB];
#pragma unroll
    for (int mb = 0; mb < MB; mb++)
#pragma unroll
        for (int nb = 0; nb < NB; nb++) acc[mb][nb] = (f32x4){0.f, 0.f, 0.f, 0.f};

    for (int kt = 0; kt < K; kt += 64) {
        __syncthreads();
#pragma unroll
        for (int i = 0; i < BM / 32; i++) {
            int rb = i * 32 + w * 8;
            gld16(&A[(long)(m0 + rb + lr) * K + kt + sc], &As[rb * 64]);
        }
#pragma unroll
        for (int i = 0; i < BN / 32; i++) {
            int rb = i * 32 + w * 8;
            gld16(&Bt[(long)(n0 + rb + lr) * K + kt + sc], &Bs[rb * 64]);
        }
        __syncthreads();
#pragma unroll
        for (int kh = 0; kh < 2; kh++) {
            bf16x8 af[MB], bfr[NB];
#pragma unroll
            for (int mb = 0; mb < MB; mb++)
                af[mb] = *(const bf16x8*)&As[(wr * (BM / 2) + mb * 16 + l16) * 64 +
                                             (((kh * 4 + quad) ^ x7) * 8)];
#pragma unroll
            for (int nb = 0; nb < NB; nb++)
                bfr[nb] = *(const bf16x8*)&Bs[(wc * (BN / 2) + nb * 16 + l16) * 64 +
                                              (((kh * 4 + quad) ^ x7) * 8)];
#pragma unroll
            for (int mb = 0; mb < MB; mb++)
#pragma unroll
                for (int nb = 0; nb < NB; nb++)
                    acc[mb][nb] = __builtin_amdgcn_mfma_f32_16x16x32_bf16(af[mb], bfr[nb], acc[mb][nb], 0, 0, 0);
        }
    }

    int mbase = m0 + wr * (BM / 2), nbase = n0 + wc * (BN / 2);
#pragma unroll
    for (int mb = 0; mb < MB; mb++)
#pragma unroll
        for (int nb = 0; nb < NB; nb++) {
            int r0 = mbase + mb * 16 + quad * 4;
            int c = nbase + nb * 16 + l16;
#pragma unroll
            for (int r = 0; r < 4; r++) {
                float v = acc[mb][nb][r];
                long idx = (long)(r0 + r) * N + c;
                if (EPI == 0) {
                    Cb[idx] = f2bs(v);
                } else if (EPI == 1) {
                    Cf[idx] = resid[idx] + v;
                } else if (EPI == 2) {
                    float xg = v + bias[c];
                    Cb[idx] = f2bs(xg * 0.5f * (1.0f + erff(xg * 0.70710678118f)));
                } else {
                    Cf[idx] = resid[idx] + v + bias[c];
                }
            }
        }
}

// ---------------- flash attention: QT=128 q-rows/block (8 waves), KT=64 keys/tile ----------------
// Per wave: 16 q-rows; S^T QK^T, in-lane softmax, in-register P.
// PV via 16x16x32 MFMA with PERMUTED contraction index (MFMA sums over k in any order):
// A = concat of two in-lane P quads, B = concat of the two bf16x4 V^T reads.
// K staged via global_load_lds DMA; V via register prefetch + pack into Vs[d][kv] s72.
// Double-buffered, one barrier per tile. defer-max THR=8 (T13). exp2 via raw v_exp_f32.
__global__ __launch_bounds__(512, 6) void attn(const u16* __restrict__ QKV, u16* __restrict__ O) {
    __shared__ u16 Ks[2][64 * 64];    // [buf][kv][chunk-swizzled d]  (DMA-staged)
    __shared__ u16 Vs[2][64 * 72];    // [buf][d][kv], stride 72      (reg-packed)
    int lin = blockIdx.x;
    int cpx = gridDim.x >> 3;                 // gridDim.x divisible by 8
    int l = (lin & 7) * cpx + (lin >> 3);     // XCD-chunked bijection
    int q0 = (l & 7) * 128;                   // SEQ/128 = 8 q-chunks
    int hb = l >> 3;
    int h = hb % NHEAD;
    int b = hb / NHEAD;
    int t = threadIdx.x;
    int lane = t & 63, w = t >> 6;            // w in 0..7
    int quad = lane >> 4, l16 = lane & 15;
    int x7 = l16 & 7;

    const long rs = 3 * DIM;  // 2304
    const u16* base = QKV + (long)b * SEQ * rs;

    // Q fragments: wave w owns rows q0 + w*16 .. +15
    bf16x8 qf0, qf1;
    {
        int qrow = q0 + w * 16 + l16;
        qf0 = *(const bf16x8*)&base[(long)qrow * rs + h * 64 + quad * 8];
        qf1 = *(const bf16x8*)&base[(long)qrow * rs + h * 64 + 32 + quad * 8];
    }

    f32x4 o[4];
#pragma unroll
    for (int dt = 0; dt < 4; dt++) o[dt] = (f32x4){0.f, 0.f, 0.f, 0.f};
    float m_run = -1e30f;
    float l_run = 0.f;
    const float L2E8 = 11.54156032f;  // 8 * log2(e)

    // ---- staging sources ----
    // K DMA: wave w stages rows w*8..+7 in ONE gld16 (8 lanes/row, 16B chunks,
    //        source chunk pre-swizzled (lc ^ lr); row&7 == lr since w*8 is 8-aligned).
    int lr = lane >> 3, lc = lane & 7;
    int sc = (lc ^ lr) * 8;
    const u16* kA = &base[(long)(w * 8 + lr) * rs + DIM + h * 64 + sc];
    // V regs: thread t loads V rows 2vc,2vc+1 (vc=t&31), d-group vo*4..+3 (vo=t>>5, 0..15)
    int vc = t & 31, vo = t >> 5;
    const u16* vptr = &base[(long)(2 * vc) * rs + 2 * DIM + h * 64 + vo * 4];
    const long kstep = (long)64 * rs;

    bf16x4 vp0, vp1;
    // ---- prologue: tile 0 ----
    gld16(kA, &Ks[0][(w * 8) * 64]);
    kA += kstep;
    vp0 = *(const bf16x4*)&vptr[0];
    vp1 = *(const bf16x4*)&vptr[rs];
    vptr += kstep;
#pragma unroll
    for (int j = 0; j < 4; j++) {
        u32 pk = (u32)(u16)vp0[j] | ((u32)(u16)vp1[j] << 16);
        *(u32*)&Vs[0][(vo * 4 + j) * 72 + 2 * vc] = pk;
    }
    // V regs for tile 1
    vp0 = *(const bf16x4*)&vptr[0];
    vp1 = *(const bf16x4*)&vptr[rs];
    vptr += kstep;
    __syncthreads();   // drains K DMA (vmcnt) + V ds_writes (lgkm) before reads

    for (int it = 0; it < SEQ / 64; it++) {
        int cur = it & 1;
        if (it < SEQ / 64 - 1) {
            int nb = cur ^ 1;
            // K DMA for tile it+1 (buf nb fully read in iter it-1; barrier passed)
            gld16(kA, &Ks[nb][(w * 8) * 64]);
            kA += kstep;
            // V write for tile it+1 (regs loaded one iteration ago)
#pragma unroll
            for (int j = 0; j < 4; j++) {
                u32 pk = (u32)(u16)vp0[j] | ((u32)(u16)vp1[j] << 16);
                *(u32*)&Vs[nb][(vo * 4 + j) * 72 + 2 * vc] = pk;
            }
            if (it < SEQ / 64 - 2) {
                vp0 = *(const bf16x4*)&vptr[0];
                vp1 = *(const bf16x4*)&vptr[rs];
                vptr += kstep;
            }
        }

        // ---- QK^T from buf[cur]: lane (quad,l16) gets s[jb][r] = S[q=l16][kv=jb*16+quad*4+r]
        f32x4 s[4];
#pragma unroll
        for (int jb = 0; jb < 4; jb++) {
            int row = jb * 16 + l16;
            bf16x8 kf0 = *(const bf16x8*)&Ks[cur][row * 64 + ((quad ^ x7) * 8)];
            bf16x8 kf1 = *(const bf16x8*)&Ks[cur][row * 64 + (((4 + quad) ^ x7) * 8)];
            f32x4 z = (f32x4){0.f, 0.f, 0.f, 0.f};
            z = __builtin_amdgcn_mfma_f32_16x16x32_bf16(kf0, qf0, z, 0, 0, 0);
            z = __builtin_amdgcn_mfma_f32_16x16x32_bf16(kf1, qf1, z, 0, 0, 0);
            s[jb] = z;
        }

        // ---- softmax (vectorized)
        f32x4 mx = __builtin_elementwise_max(__builtin_elementwise_max(s[0], s[1]),
                                             __builtin_elementwise_max(s[2], s[3]));
        float m1 = fmaxf(fmaxf(mx[0], mx[1]), fmaxf(mx[2], mx[3]));
        m1 = fmaxf(m1, __shfl_xor(m1, 16, 64));
        m1 = fmaxf(m1, __shfl_xor(m1, 32, 64));

        // defer-max (T13, THR=8): skip O/l rescale unless some row's max grew by >8
        // (P then bounded by e^8 ~ 2981 -- safe in f32 sums / bf16 P).
        float mn = m_run;
        int resc = __any(m1 > mn + 8.0f);
        if (resc) mn = fmaxf(mn, m1);
        float mn8 = mn * L2E8;
        f32x4 cmul = {L2E8, L2E8, L2E8, L2E8};
        f32x4 cadd = {-mn8, -mn8, -mn8, -mn8};
#pragma unroll
        for (int jb = 0; jb < 4; jb++) {
            f32x4 e = s[jb] * cmul + cadd;
            e[0] = fexp2(e[0]); e[1] = fexp2(e[1]);
            e[2] = fexp2(e[2]); e[3] = fexp2(e[3]);
            s[jb] = e;
        }
        f32x4 sv = (s[0] + s[1]) + (s[2] + s[3]);
        float rsum = (sv[0] + sv[1]) + (sv[2] + sv[3]);
        rsum += __shfl_xor(rsum, 16, 64);
        rsum += __shfl_xor(rsum, 32, 64);

        if (resc) {
            float alpha = fexp2((m_run - mn) * L2E8);
            m_run = mn;
            float a0 = __shfl(alpha, quad * 4 + 0, 16);
            float a1 = __shfl(alpha, quad * 4 + 1, 16);
            float a2 = __shfl(alpha, quad * 4 + 2, 16);
            float a3 = __shfl(alpha, quad * 4 + 3, 16);
#pragma unroll
            for (int dt = 0; dt < 4; dt++) {
                o[dt][0] *= a0; o[dt][1] *= a1;
                o[dt][2] *= a2; o[dt][3] *= a3;
            }
            l_run = l_run * alpha + rsum;
        } else {
            l_run += rsum;
        }

        // ---- PV: 16x16x32 with permuted k. A = concat(P[jb0],P[jb1]) in-lane;
        //          B = concat of the two bf16x4 V^T reads (same addresses as K=16 version).
#pragma unroll
        for (int jp = 0; jp < 2; jp++) {
            int jb0 = 2 * jp, jb1 = 2 * jp + 1;
            union { u32 u[4]; bf16x8 v; } pa;
            pa.u[0] = packbf2(s[jb0][0], s[jb0][1]);
            pa.u[1] = packbf2(s[jb0][2], s[jb0][3]);
            pa.u[2] = packbf2(s[jb1][0], s[jb1][1]);
            pa.u[3] = packbf2(s[jb1][2], s[jb1][3]);
#pragma unroll
            for (int dt = 0; dt < 4; dt++) {
                union { bf16x4 h[2]; bf16x8 v; } vb;
                vb.h[0] = *(const bf16x4*)&Vs[cur][(dt * 16 + l16) * 72 + jb0 * 16 + quad * 4];
                vb.h[1] = *(const bf16x4*)&Vs[cur][(dt * 16 + l16) * 72 + jb1 * 16 + quad * 4];
                o[dt] = __builtin_amdgcn_mfma_f32_16x16x32_bf16(pa.v, vb.v, o[dt], 0, 0, 0);
            }
        }

        if (it < SEQ / 64 - 1) __syncthreads();   // protects buf[cur] overwrite next iter
    }

    // epilogue: rows quad*4+r, cols dt*16+l16
    {
        float l0 = __shfl(l_run, quad * 4 + 0, 16);
        float l1 = __shfl(l_run, quad * 4 + 1, 16);
        float l2 = __shfl(l_run, quad * 4 + 2, 16);
        float l3 = __shfl(l_run, quad * 4 + 3, 16);
        u16* orow = O + ((long)(b * SEQ + q0 + w * 16)) * DIM + h * 64;
#pragma unroll
        for (int dt = 0; dt < 4; dt++) {
            u32 p01 = packbf2(o[dt][0] / l0, o[dt][1] / l1);
            u32 p23 = packbf2(o[dt][2] / l2, o[dt][3] / l3);
            int cidx = dt * 16 + l16;
            orow[(long)(quad * 4 + 0) * DIM + cidx] = (u16)p01;
            orow[(long)(quad * 4 + 1) * DIM + cidx] = (u16)(p01 >> 16);
            orow[(long)(quad * 4 + 2) * DIM + cidx] = (u16)p23;
            orow[(long)(quad * 4 + 3) * DIM + cidx] = (u16)(p23 >> 16);
        }
    }
}

extern "C" void kernel_launch(void* const* d_in, const int* in_sizes, int n_in,
                              void* d_out, int out_size, void* d_ws, size_t ws_size,
                              hipStream_t stream) {
    const float* x     = (const float*)d_in[0];
    const float* ln1w  = (const float*)d_in[1];
    const float* ln1b  = (const float*)d_in[2];
    const float* ln2w  = (const float*)d_in[3];
    const float* ln2b  = (const float*)d_in[4];
    const float* wqkv  = (const float*)d_in[5];
    const float* wproj = (const float*)d_in[6];
    const float* wfc1  = (const float*)d_in[7];
    const float* bfc1  = (const float*)d_in[8];
    const float* wfc2  = (const float*)d_in[9];
    const float* bfc2  = (const float*)d_in[10];
    float* out = (float*)d_out;

    char* ws = (char*)d_ws;
    size_t off = 0;
    auto alloc = [&](size_t bytes) {
        void* p = ws + off;
        off = (off + bytes + 255) & ~(size_t)255;
        return p;
    };
    u16* wt_qkv  = (u16*)alloc((size_t)3 * DIM * DIM * 2);
    u16* wt_proj = (u16*)alloc((size_t)DIM * DIM * 2);
    u16* wt_fc1  = (u16*)alloc((size_t)HIDDEN * DIM * 2);
    u16* wt_fc2  = (u16*)alloc((size_t)DIM * HIDDEN * 2);
    u16* hbuf    = (u16*)alloc((size_t)ROWS * DIM * 2);      // ln1 out -> attn out -> ln2 out
    u16* gbuf    = (u16*)alloc((size_t)ROWS * HIDDEN * 2);   // gelu out
    size_t qkv_bytes = (size_t)ROWS * 3 * DIM * 2;           // 37.75 MB
    u16* qkvfull = (off + qkv_bytes + 1024 <= ws_size) ? (u16*)alloc(qkv_bytes) : nullptr;

    // 1. weights -> bf16 transposed (single fused launch)
    wtrans4<<<2880, 256, 0, stream>>>(wqkv, wt_qkv, wproj, wt_proj,
                                      wfc1, wt_fc1, wfc2, wt_fc2);

    // 2. ln1
    lnorm<<<ROWS, 256, 0, stream>>>(x, ln1w, ln1b, hbuf);

    // 3. qkv + attention
    if (qkvfull) {
        gemm_bt<128, 128, 0><<<dim3(3 * DIM / 128, ROWS / 128), 256, 0, stream>>>(
            hbuf, wt_qkv, ROWS, 3 * DIM, DIM, qkvfull, nullptr, nullptr, nullptr);
        attn<<<(SEQ / 128) * NHEAD * BATCH, 512, 0, stream>>>(qkvfull, hbuf);
    } else {
        u16* qd = (u16*)d_out;
        for (int c = 0; c < ROWS / CHUNKR; c++) {
            const u16* hA = hbuf + (size_t)c * CHUNKR * DIM;
            gemm_bt<128, 128, 0><<<dim3(3 * DIM / 128, CHUNKR / 128), 256, 0, stream>>>(
                hA, wt_qkv, CHUNKR, 3 * DIM, DIM, qd, nullptr, nullptr, nullptr);
            attn<<<(SEQ / 128) * NHEAD * CHUNKB, 512, 0, stream>>>(
                qd, hbuf + (size_t)c * CHUNKR * DIM);
        }
    }

    // 4. x1 = x + attn_out @ w_proj  (fp32 into d_out)
    gemm_bt<128, 64, 1><<<dim3(DIM / 64, ROWS / 128), 256, 0, stream>>>(
        hbuf, wt_proj, ROWS, DIM, DIM, nullptr, out, x, nullptr);

    // 5. ln2
    lnorm<<<ROWS, 256, 0, stream>>>(out, ln2w, ln2b, hbuf);

    // 6. g = gelu(hbuf @ w_fc1 + b_fc1)  (64x64: 128-row tile regressed in R8 — 384-block
    //    grid = 1.5 blocks/CU ragged round; 768 blocks = 3/CU is better shaped)
    gemm_bt<64, 64, 2><<<dim3(HIDDEN / 64, ROWS / 64), 256, 0, stream>>>(
        hbuf, wt_fc1, ROWS, HIDDEN, DIM, gbuf, nullptr, nullptr, bfc1);

    // 7. out = x1 + g @ w_fc2 + b_fc2  (fp32, in-place over x1)
    gemm_bt<128, 64, 3><<<dim3(DIM / 64, ROWS / 128), 256, 0, stream>>>(
        gbuf, wt_fc2, ROWS, DIM, HIDDEN, nullptr, out, out, bfc2);
}

// Round 10
// 240.571 us; speedup vs baseline: 1.1399x; 1.0763x over previous
//
#include <hip/hip_runtime.h>
#include <hip/hip_bf16.h>
#include <math.h>

#define DIM 768
#define NHEAD 12
#define HD 64
#define HIDDEN 384
#define BATCH 8
#define SEQ 1024
#define ROWS (BATCH*SEQ)
#define CHUNKB 4                 // batches per qkv/attn chunk (fallback path)
#define CHUNKR (CHUNKB*SEQ)

typedef short bf16x8 __attribute__((ext_vector_type(8)));
typedef short bf16x4 __attribute__((ext_vector_type(4)));
typedef float f32x4 __attribute__((ext_vector_type(4)));
typedef unsigned short u16;
typedef unsigned int u32;

__device__ __forceinline__ u16 f2bs(float f) {
    unsigned int u = __float_as_uint(f);
    unsigned int r = (u + 0x7FFFu + ((u >> 16) & 1u)) >> 16;
    return (u16)r;
}

// HW packed bf16 convert (v_cvt_pk_bf16_f32 on gfx950), RNE
__device__ __forceinline__ u32 packbf2(float a, float b) {
    __hip_bfloat162 h = __float22bfloat162_rn(make_float2(a, b));
    u32 r;
    __builtin_memcpy(&r, &h, 4);
    return r;
}

// raw v_exp_f32 (1 instr): exp2f() lowers to the OCML range-checked libcall (~8 instr).
// Safe here: args are finite, <= 0; v_exp flushes large-negative to 0, ~1 ulp accuracy.
__device__ __forceinline__ float fexp2(float x) {
    return __builtin_amdgcn_exp2f(x);
}

// async global->LDS DMA, 16 B/lane; LDS dest = wave-uniform base + lane*16
__device__ __forceinline__ void gld16(const u16* g, u16* l) {
    __builtin_amdgcn_global_load_lds(
        (const __attribute__((address_space(1))) unsigned int*)g,
        (__attribute__((address_space(3))) unsigned int*)l, 16, 0, 0);
}

// ---------------- fused tiled weight transpose: Wt[n][k] = bf16(W[k][n]) ----------------
// All four weight matrices in ONE launch. 2880 32x32 tiles:
//   [0,1728) wqkv | [1728,2304) wproj | [2304,2592) wfc1 | [2592,2880) wfc2
__global__ __launch_bounds__(256) void wtrans4(const float* __restrict__ W0, u16* __restrict__ T0,
                                               const float* __restrict__ W1, u16* __restrict__ T1,
                                               const float* __restrict__ W2, u16* __restrict__ T2,
                                               const float* __restrict__ W3, u16* __restrict__ T3) {
    __shared__ float tile[32][33];
    int id = blockIdx.x;
    const float* W; u16* T; int K, N, nt;
    if (id < 1728)      {            W = W0; T = T0; K = 768; N = 2304; nt = 72; }
    else if (id < 2304) { id -= 1728; W = W1; T = T1; K = 768; N = 768;  nt = 24; }
    else if (id < 2592) { id -= 2304; W = W2; T = T2; K = 768; N = 384;  nt = 12; }
    else                { id -= 2592; W = W3; T = T3; K = 384; N = 768;  nt = 24; }
    int n0 = (id % nt) * 32, k0 = (id / nt) * 32;
    int tx = threadIdx.x & 31, ty = threadIdx.x >> 5;
#pragma unroll
    for (int i = 0; i < 4; i++)
        tile[ty + i * 8][tx] = W[(long)(k0 + ty + i * 8) * N + n0 + tx];
    __syncthreads();
#pragma unroll
    for (int i = 0; i < 4; i++)
        T[(long)(n0 + ty + i * 8) * K + k0 + tx] = f2bs(tile[tx][ty + i * 8]);
}

// ---------------- layernorm: fp32 in -> bf16 out, one block per row ----------------
__global__ __launch_bounds__(256) void lnorm(const float* __restrict__ X,
                                             const float* __restrict__ w,
                                             const float* __restrict__ b,
                                             u16* __restrict__ Y) {
    int row = blockIdx.x;
    const float* xr = X + (long)row * DIM;
    int t = threadIdx.x;
    float v0 = xr[t], v1 = xr[t + 256], v2 = xr[t + 512];
    float s = v0 + v1 + v2;
    float s2 = v0 * v0 + v1 * v1 + v2 * v2;
    for (int off = 1; off < 64; off <<= 1) {
        s  += __shfl_xor(s,  off, 64);
        s2 += __shfl_xor(s2, off, 64);
    }
    __shared__ float ss[4], ss2[4];
    int wid = t >> 6;
    if ((t & 63) == 0) { ss[wid] = s; ss2[wid] = s2; }
    __syncthreads();
    s  = ss[0] + ss[1] + ss[2] + ss[3];
    s2 = ss2[0] + ss2[1] + ss2[2] + ss2[3];
    float mu = s * (1.0f / DIM);
    float var = s2 * (1.0f / DIM) - mu * mu;
    float rstd = rsqrtf(var + 1e-5f);
    u16* yr = Y + (long)row * DIM;
    yr[t]       = f2bs((v0 - mu) * rstd * w[t]       + b[t]);
    yr[t + 256] = f2bs((v1 - mu) * rstd * w[t + 256] + b[t + 256]);
    yr[t + 512] = f2bs((v2 - mu) * rstd * w[t + 512] + b[t + 512]);
}

// ---------------- bf16 MFMA GEMM, C = A[M,K] @ Bt[N,K]^T, BMxBNx64 tiles ----------------
// 1D grid with XCD-chunked swizzle (T1): HW maps linear block id round-robin to XCDs, so
// the chunked bijection gives each XCD a contiguous m-stripe x all-n region whose A+B
// working set fits its private 4MB L2 (qkv: 1.5+3.4MB; proj/fc: <2.6MB). nblk = N/BN.
// Staging via global_load_lds width=16 into unpadded stride-64 LDS with XOR swizzle.
// EPI: 0 = bf16 out; 1 = f32 out + resid; 2 = bf16 out + bias + exact GELU; 3 = f32 out + resid + bias
template <int BM, int BN, int EPI>
__global__ __launch_bounds__(256) void gemm_bt(const u16* __restrict__ A,
                                               const u16* __restrict__ Bt,
                                               int M, int N, int K, int nblk,
                                               u16* __restrict__ Cb,
                                               float* __restrict__ Cf,
                                               const float* __restrict__ resid,
                                               const float* __restrict__ bias) {
    constexpr int MB = BM / 32, NB = BN / 32;
    __shared__ u16 As[BM * 64];
    __shared__ u16 Bs[BN * 64];
    int lin = blockIdx.x;
    int cpx = gridDim.x >> 3;                 // grid divisible by 8 at all call sites
    int swz = (lin & 7) * cpx + (lin >> 3);   // XCD-chunked bijection
    int m0 = (swz / nblk) * BM;
    int n0 = (swz % nblk) * BN;
    int t = threadIdx.x;
    int lane = t & 63, w = t >> 6;
    int quad = lane >> 4, l16 = lane & 15;
    int wr = w >> 1, wc = w & 1;
    int lr = lane >> 3, lc = lane & 7;
    int sc = (lc ^ lr) * 8;      // swizzled source chunk offset (u16 units)
    int x7 = l16 & 7;            // row&7 for fragment reads

    f32x4 acc[MB][NB];
#pragma unroll
    for (int mb = 0; mb < MB; mb++)
#pragma unroll
        for (int nb = 0; nb < NB; nb++) acc[mb][nb] = (f32x4){0.f, 0.f, 0.f, 0.f};

    for (int kt = 0; kt < K; kt += 64) {
        __syncthreads();
#pragma unroll
        for (int i = 0; i < BM / 32; i++) {
            int rb = i * 32 + w * 8;
            gld16(&A[(long)(m0 + rb + lr) * K + kt + sc], &As[rb * 64]);
        }
#pragma unroll
        for (int i = 0; i < BN / 32; i++) {
            int rb = i * 32 + w * 8;
            gld16(&Bt[(long)(n0 + rb + lr) * K + kt + sc], &Bs[rb * 64]);
        }
        __syncthreads();
#pragma unroll
        for (int kh = 0; kh < 2; kh++) {
            bf16x8 af[MB], bfr[NB];
#pragma unroll
            for (int mb = 0; mb < MB; mb++)
                af[mb] = *(const bf16x8*)&As[(wr * (BM / 2) + mb * 16 + l16) * 64 +
                                             (((kh * 4 + quad) ^ x7) * 8)];
#pragma unroll
            for (int nb = 0; nb < NB; nb++)
                bfr[nb] = *(const bf16x8*)&Bs[(wc * (BN / 2) + nb * 16 + l16) * 64 +
                                              (((kh * 4 + quad) ^ x7) * 8)];
#pragma unroll
            for (int mb = 0; mb < MB; mb++)
#pragma unroll
                for (int nb = 0; nb < NB; nb++)
                    acc[mb][nb] = __builtin_amdgcn_mfma_f32_16x16x32_bf16(af[mb], bfr[nb], acc[mb][nb], 0, 0, 0);
        }
    }

    int mbase = m0 + wr * (BM / 2), nbase = n0 + wc * (BN / 2);
#pragma unroll
    for (int mb = 0; mb < MB; mb++)
#pragma unroll
        for (int nb = 0; nb < NB; nb++) {
            int r0 = mbase + mb * 16 + quad * 4;
            int c = nbase + nb * 16 + l16;
#pragma unroll
            for (int r = 0; r < 4; r++) {
                float v = acc[mb][nb][r];
                long idx = (long)(r0 + r) * N + c;
                if (EPI == 0) {
                    Cb[idx] = f2bs(v);
                } else if (EPI == 1) {
                    Cf[idx] = resid[idx] + v;
                } else if (EPI == 2) {
                    float xg = v + bias[c];
                    Cb[idx] = f2bs(xg * 0.5f * (1.0f + erff(xg * 0.70710678118f)));
                } else {
                    Cf[idx] = resid[idx] + v + bias[c];
                }
            }
        }
}

// ---------------- flash attention: QT=128 q-rows/block (8 waves), KT=64 keys/tile ----------------
// Per wave: 16 q-rows; S^T QK^T, in-lane softmax, in-register P.
// PV via 16x16x32 MFMA with PERMUTED contraction index (MFMA sums over k in any order):
// A = concat of two in-lane P quads, B = concat of the two bf16x4 V^T reads.
// K staged via global_load_lds DMA; V via register prefetch + pack into Vs[d][kv] s72.
// Double-buffered, one barrier per tile. defer-max THR=8 (T13). exp2 via raw v_exp_f32.
__global__ __launch_bounds__(512, 6) void attn(const u16* __restrict__ QKV, u16* __restrict__ O) {
    __shared__ u16 Ks[2][64 * 64];    // [buf][kv][chunk-swizzled d]  (DMA-staged)
    __shared__ u16 Vs[2][64 * 72];    // [buf][d][kv], stride 72      (reg-packed)
    int lin = blockIdx.x;
    int cpx = gridDim.x >> 3;                 // gridDim.x divisible by 8
    int l = (lin & 7) * cpx + (lin >> 3);     // XCD-chunked bijection
    int q0 = (l & 7) * 128;                   // SEQ/128 = 8 q-chunks
    int hb = l >> 3;
    int h = hb % NHEAD;
    int b = hb / NHEAD;
    int t = threadIdx.x;
    int lane = t & 63, w = t >> 6;            // w in 0..7
    int quad = lane >> 4, l16 = lane & 15;
    int x7 = l16 & 7;

    const long rs = 3 * DIM;  // 2304
    const u16* base = QKV + (long)b * SEQ * rs;

    // Q fragments: wave w owns rows q0 + w*16 .. +15
    bf16x8 qf0, qf1;
    {
        int qrow = q0 + w * 16 + l16;
        qf0 = *(const bf16x8*)&base[(long)qrow * rs + h * 64 + quad * 8];
        qf1 = *(const bf16x8*)&base[(long)qrow * rs + h * 64 + 32 + quad * 8];
    }

    f32x4 o[4];
#pragma unroll
    for (int dt = 0; dt < 4; dt++) o[dt] = (f32x4){0.f, 0.f, 0.f, 0.f};
    float m_run = -1e30f;
    float l_run = 0.f;
    const float L2E8 = 11.54156032f;  // 8 * log2(e)

    // ---- staging sources ----
    // K DMA: wave w stages rows w*8..+7 in ONE gld16 (8 lanes/row, 16B chunks,
    //        source chunk pre-swizzled (lc ^ lr); row&7 == lr since w*8 is 8-aligned).
    int lr = lane >> 3, lc = lane & 7;
    int sc = (lc ^ lr) * 8;
    const u16* kA = &base[(long)(w * 8 + lr) * rs + DIM + h * 64 + sc];
    // V regs: thread t loads V rows 2vc,2vc+1 (vc=t&31), d-group vo*4..+3 (vo=t>>5, 0..15)
    int vc = t & 31, vo = t >> 5;
    const u16* vptr = &base[(long)(2 * vc) * rs + 2 * DIM + h * 64 + vo * 4];
    const long kstep = (long)64 * rs;

    bf16x4 vp0, vp1;
    // ---- prologue: tile 0 ----
    gld16(kA, &Ks[0][(w * 8) * 64]);
    kA += kstep;
    vp0 = *(const bf16x4*)&vptr[0];
    vp1 = *(const bf16x4*)&vptr[rs];
    vptr += kstep;
#pragma unroll
    for (int j = 0; j < 4; j++) {
        u32 pk = (u32)(u16)vp0[j] | ((u32)(u16)vp1[j] << 16);
        *(u32*)&Vs[0][(vo * 4 + j) * 72 + 2 * vc] = pk;
    }
    // V regs for tile 1
    vp0 = *(const bf16x4*)&vptr[0];
    vp1 = *(const bf16x4*)&vptr[rs];
    vptr += kstep;
    __syncthreads();   // drains K DMA (vmcnt) + V ds_writes (lgkm) before reads

    for (int it = 0; it < SEQ / 64; it++) {
        int cur = it & 1;
        if (it < SEQ / 64 - 1) {
            int nb = cur ^ 1;
            // K DMA for tile it+1 (buf nb fully read in iter it-1; barrier passed)
            gld16(kA, &Ks[nb][(w * 8) * 64]);
            kA += kstep;
            // V write for tile it+1 (regs loaded one iteration ago)
#pragma unroll
            for (int j = 0; j < 4; j++) {
                u32 pk = (u32)(u16)vp0[j] | ((u32)(u16)vp1[j] << 16);
                *(u32*)&Vs[nb][(vo * 4 + j) * 72 + 2 * vc] = pk;
            }
            if (it < SEQ / 64 - 2) {
                vp0 = *(const bf16x4*)&vptr[0];
                vp1 = *(const bf16x4*)&vptr[rs];
                vptr += kstep;
            }
        }

        // ---- QK^T from buf[cur]: lane (quad,l16) gets s[jb][r] = S[q=l16][kv=jb*16+quad*4+r]
        f32x4 s[4];
#pragma unroll
        for (int jb = 0; jb < 4; jb++) {
            int row = jb * 16 + l16;
            bf16x8 kf0 = *(const bf16x8*)&Ks[cur][row * 64 + ((quad ^ x7) * 8)];
            bf16x8 kf1 = *(const bf16x8*)&Ks[cur][row * 64 + (((4 + quad) ^ x7) * 8)];
            f32x4 z = (f32x4){0.f, 0.f, 0.f, 0.f};
            z = __builtin_amdgcn_mfma_f32_16x16x32_bf16(kf0, qf0, z, 0, 0, 0);
            z = __builtin_amdgcn_mfma_f32_16x16x32_bf16(kf1, qf1, z, 0, 0, 0);
            s[jb] = z;
        }

        // ---- softmax (vectorized)
        f32x4 mx = __builtin_elementwise_max(__builtin_elementwise_max(s[0], s[1]),
                                             __builtin_elementwise_max(s[2], s[3]));
        float m1 = fmaxf(fmaxf(mx[0], mx[1]), fmaxf(mx[2], mx[3]));
        m1 = fmaxf(m1, __shfl_xor(m1, 16, 64));
        m1 = fmaxf(m1, __shfl_xor(m1, 32, 64));

        // defer-max (T13, THR=8): skip O/l rescale unless some row's max grew by >8
        // (P then bounded by e^8 ~ 2981 -- safe in f32 sums / bf16 P).
        float mn = m_run;
        int resc = __any(m1 > mn + 8.0f);
        if (resc) mn = fmaxf(mn, m1);
        float mn8 = mn * L2E8;
        f32x4 cmul = {L2E8, L2E8, L2E8, L2E8};
        f32x4 cadd = {-mn8, -mn8, -mn8, -mn8};
#pragma unroll
        for (int jb = 0; jb < 4; jb++) {
            f32x4 e = s[jb] * cmul + cadd;
            e[0] = fexp2(e[0]); e[1] = fexp2(e[1]);
            e[2] = fexp2(e[2]); e[3] = fexp2(e[3]);
            s[jb] = e;
        }
        f32x4 sv = (s[0] + s[1]) + (s[2] + s[3]);
        float rsum = (sv[0] + sv[1]) + (sv[2] + sv[3]);
        rsum += __shfl_xor(rsum, 16, 64);
        rsum += __shfl_xor(rsum, 32, 64);

        if (resc) {
            float alpha = fexp2((m_run - mn) * L2E8);
            m_run = mn;
            float a0 = __shfl(alpha, quad * 4 + 0, 16);
            float a1 = __shfl(alpha, quad * 4 + 1, 16);
            float a2 = __shfl(alpha, quad * 4 + 2, 16);
            float a3 = __shfl(alpha, quad * 4 + 3, 16);
#pragma unroll
            for (int dt = 0; dt < 4; dt++) {
                o[dt][0] *= a0; o[dt][1] *= a1;
                o[dt][2] *= a2; o[dt][3] *= a3;
            }
            l_run = l_run * alpha + rsum;
        } else {
            l_run += rsum;
        }

        // ---- PV: 16x16x32 with permuted k. A = concat(P[jb0],P[jb1]) in-lane;
        //          B = concat of the two bf16x4 V^T reads (same addresses as K=16 version).
#pragma unroll
        for (int jp = 0; jp < 2; jp++) {
            int jb0 = 2 * jp, jb1 = 2 * jp + 1;
            union { u32 u[4]; bf16x8 v; } pa;
            pa.u[0] = packbf2(s[jb0][0], s[jb0][1]);
            pa.u[1] = packbf2(s[jb0][2], s[jb0][3]);
            pa.u[2] = packbf2(s[jb1][0], s[jb1][1]);
            pa.u[3] = packbf2(s[jb1][2], s[jb1][3]);
#pragma unroll
            for (int dt = 0; dt < 4; dt++) {
                union { bf16x4 h[2]; bf16x8 v; } vb;
                vb.h[0] = *(const bf16x4*)&Vs[cur][(dt * 16 + l16) * 72 + jb0 * 16 + quad * 4];
                vb.h[1] = *(const bf16x4*)&Vs[cur][(dt * 16 + l16) * 72 + jb1 * 16 + quad * 4];
                o[dt] = __builtin_amdgcn_mfma_f32_16x16x32_bf16(pa.v, vb.v, o[dt], 0, 0, 0);
            }
        }

        if (it < SEQ / 64 - 1) __syncthreads();   // protects buf[cur] overwrite next iter
    }

    // epilogue: rows quad*4+r, cols dt*16+l16. 1/l via v_rcp_f32 (l >= 1, 1-ulp ok for bf16)
    {
        float l0 = __builtin_amdgcn_rcpf(__shfl(l_run, quad * 4 + 0, 16));
        float l1 = __builtin_amdgcn_rcpf(__shfl(l_run, quad * 4 + 1, 16));
        float l2 = __builtin_amdgcn_rcpf(__shfl(l_run, quad * 4 + 2, 16));
        float l3 = __builtin_amdgcn_rcpf(__shfl(l_run, quad * 4 + 3, 16));
        u16* orow = O + ((long)(b * SEQ + q0 + w * 16)) * DIM + h * 64;
#pragma unroll
        for (int dt = 0; dt < 4; dt++) {
            u32 p01 = packbf2(o[dt][0] * l0, o[dt][1] * l1);
            u32 p23 = packbf2(o[dt][2] * l2, o[dt][3] * l3);
            int cidx = dt * 16 + l16;
            orow[(long)(quad * 4 + 0) * DIM + cidx] = (u16)p01;
            orow[(long)(quad * 4 + 1) * DIM + cidx] = (u16)(p01 >> 16);
            orow[(long)(quad * 4 + 2) * DIM + cidx] = (u16)p23;
            orow[(long)(quad * 4 + 3) * DIM + cidx] = (u16)(p23 >> 16);
        }
    }
}

extern "C" void kernel_launch(void* const* d_in, const int* in_sizes, int n_in,
                              void* d_out, int out_size, void* d_ws, size_t ws_size,
                              hipStream_t stream) {
    const float* x     = (const float*)d_in[0];
    const float* ln1w  = (const float*)d_in[1];
    const float* ln1b  = (const float*)d_in[2];
    const float* ln2w  = (const float*)d_in[3];
    const float* ln2b  = (const float*)d_in[4];
    const float* wqkv  = (const float*)d_in[5];
    const float* wproj = (const float*)d_in[6];
    const float* wfc1  = (const float*)d_in[7];
    const float* bfc1  = (const float*)d_in[8];
    const float* wfc2  = (const float*)d_in[9];
    const float* bfc2  = (const float*)d_in[10];
    float* out = (float*)d_out;

    char* ws = (char*)d_ws;
    size_t off = 0;
    auto alloc = [&](size_t bytes) {
        void* p = ws + off;
        off = (off + bytes + 255) & ~(size_t)255;
        return p;
    };
    u16* wt_qkv  = (u16*)alloc((size_t)3 * DIM * DIM * 2);
    u16* wt_proj = (u16*)alloc((size_t)DIM * DIM * 2);
    u16* wt_fc1  = (u16*)alloc((size_t)HIDDEN * DIM * 2);
    u16* wt_fc2  = (u16*)alloc((size_t)DIM * HIDDEN * 2);
    u16* hbuf    = (u16*)alloc((size_t)ROWS * DIM * 2);      // ln1 out -> attn out -> ln2 out
    u16* gbuf    = (u16*)alloc((size_t)ROWS * HIDDEN * 2);   // gelu out
    size_t qkv_bytes = (size_t)ROWS * 3 * DIM * 2;           // 37.75 MB
    u16* qkvfull = (off + qkv_bytes + 1024 <= ws_size) ? (u16*)alloc(qkv_bytes) : nullptr;

    // 1. weights -> bf16 transposed (single fused launch)
    wtrans4<<<2880, 256, 0, stream>>>(wqkv, wt_qkv, wproj, wt_proj,
                                      wfc1, wt_fc1, wfc2, wt_fc2);

    // 2. ln1
    lnorm<<<ROWS, 256, 0, stream>>>(x, ln1w, ln1b, hbuf);

    // 3. qkv + attention  (1D grids, XCD-chunk swizzled; all divisible by 8)
    if (qkvfull) {
        gemm_bt<128, 128, 0><<<(3 * DIM / 128) * (ROWS / 128), 256, 0, stream>>>(
            hbuf, wt_qkv, ROWS, 3 * DIM, DIM, 3 * DIM / 128, qkvfull, nullptr, nullptr, nullptr);
        attn<<<(SEQ / 128) * NHEAD * BATCH, 512, 0, stream>>>(qkvfull, hbuf);
    } else {
        u16* qd = (u16*)d_out;
        for (int c = 0; c < ROWS / CHUNKR; c++) {
            const u16* hA = hbuf + (size_t)c * CHUNKR * DIM;
            gemm_bt<128, 128, 0><<<(3 * DIM / 128) * (CHUNKR / 128), 256, 0, stream>>>(
                hA, wt_qkv, CHUNKR, 3 * DIM, DIM, 3 * DIM / 128, qd, nullptr, nullptr, nullptr);
            attn<<<(SEQ / 128) * NHEAD * CHUNKB, 512, 0, stream>>>(
                qd, hbuf + (size_t)c * CHUNKR * DIM);
        }
    }

    // 4. x1 = x + attn_out @ w_proj  (fp32 into d_out)
    gemm_bt<128, 64, 1><<<(DIM / 64) * (ROWS / 128), 256, 0, stream>>>(
        hbuf, wt_proj, ROWS, DIM, DIM, DIM / 64, nullptr, out, x, nullptr);

    // 5. ln2
    lnorm<<<ROWS, 256, 0, stream>>>(out, ln2w, ln2b, hbuf);

    // 6. g = gelu(hbuf @ w_fc1 + b_fc1)
    gemm_bt<64, 64, 2><<<(HIDDEN / 64) * (ROWS / 64), 256, 0, stream>>>(
        hbuf, wt_fc1, ROWS, HIDDEN, DIM, HIDDEN / 64, gbuf, nullptr, nullptr, bfc1);

    // 7. out = x1 + g @ w_fc2 + b_fc2  (fp32, in-place over x1)
    gemm_bt<128, 64, 3><<<(DIM / 64) * (ROWS / 128), 256, 0, stream>>>(
        gbuf, wt_fc2, ROWS, DIM, HIDDEN, DIM / 64, nullptr, out, out, bfc2);
}

// Round 11
// 235.665 us; speedup vs baseline: 1.1636x; 1.0208x over previous
//
#include <hip/hip_runtime.h>
#include <hip/hip_bf16.h>
#include <math.h>

#define DIM 768
#define NHEAD 12
#define HD 64
#define HIDDEN 384
#define BATCH 8
#define SEQ 1024
#define ROWS (BATCH*SEQ)
#define CHUNKB 4                 // batches per qkv/attn chunk (fallback path)
#define CHUNKR (CHUNKB*SEQ)

typedef short bf16x8 __attribute__((ext_vector_type(8)));
typedef short bf16x4 __attribute__((ext_vector_type(4)));
typedef float f32x4 __attribute__((ext_vector_type(4)));
typedef unsigned short u16;
typedef unsigned int u32;

__device__ __forceinline__ u16 f2bs(float f) {
    unsigned int u = __float_as_uint(f);
    unsigned int r = (u + 0x7FFFu + ((u >> 16) & 1u)) >> 16;
    return (u16)r;
}

__device__ __forceinline__ float bs2f(u16 v) {
    return __uint_as_float((u32)v << 16);
}

// HW packed bf16 convert (v_cvt_pk_bf16_f32 on gfx950), RNE
__device__ __forceinline__ u32 packbf2(float a, float b) {
    __hip_bfloat162 h = __float22bfloat162_rn(make_float2(a, b));
    u32 r;
    __builtin_memcpy(&r, &h, 4);
    return r;
}

// raw v_exp_f32 (1 instr): exp2f() lowers to the OCML range-checked libcall (~8 instr).
// Safe here: args are finite, <= 0; v_exp flushes large-negative to 0, ~1 ulp accuracy.
__device__ __forceinline__ float fexp2(float x) {
    return __builtin_amdgcn_exp2f(x);
}

// async global->LDS DMA, 16 B/lane; LDS dest = wave-uniform base + lane*16
__device__ __forceinline__ void gld16(const u16* g, u16* l) {
    __builtin_amdgcn_global_load_lds(
        (const __attribute__((address_space(1))) unsigned int*)g,
        (__attribute__((address_space(3))) unsigned int*)l, 16, 0, 0);
}

// ---------------- fused prep: ln1 (blocks [0,ROWS)) + 4x weight transpose ----------------
// wtrans tiles [ROWS, ROWS+2880): [0,1728) wqkv | [1728,2304) wproj | [2304,2592) wfc1
// | [2592,2880) wfc2. Independent work, one launch (saves a launch gap).
__global__ __launch_bounds__(256) void prep(const float* __restrict__ X,
                                            const float* __restrict__ lw,
                                            const float* __restrict__ lb,
                                            u16* __restrict__ Y,
                                            const float* __restrict__ W0, u16* __restrict__ T0,
                                            const float* __restrict__ W1, u16* __restrict__ T1,
                                            const float* __restrict__ W2, u16* __restrict__ T2,
                                            const float* __restrict__ W3, u16* __restrict__ T3) {
    __shared__ float tile[32][33];
    __shared__ float ss[4], ss2[4];
    int id = blockIdx.x;
    int t = threadIdx.x;
    if (id < ROWS) {
        // ---- layernorm row id: fp32 in -> bf16 out ----
        const float* xr = X + (long)id * DIM;
        float v0 = xr[t], v1 = xr[t + 256], v2 = xr[t + 512];
        float s = v0 + v1 + v2;
        float s2 = v0 * v0 + v1 * v1 + v2 * v2;
        for (int off = 1; off < 64; off <<= 1) {
            s  += __shfl_xor(s,  off, 64);
            s2 += __shfl_xor(s2, off, 64);
        }
        int wid = t >> 6;
        if ((t & 63) == 0) { ss[wid] = s; ss2[wid] = s2; }
        __syncthreads();
        s  = ss[0] + ss[1] + ss[2] + ss[3];
        s2 = ss2[0] + ss2[1] + ss2[2] + ss2[3];
        float mu = s * (1.0f / DIM);
        float var = s2 * (1.0f / DIM) - mu * mu;
        float rstd = rsqrtf(var + 1e-5f);
        u16* yr = Y + (long)id * DIM;
        yr[t]       = f2bs((v0 - mu) * rstd * lw[t]       + lb[t]);
        yr[t + 256] = f2bs((v1 - mu) * rstd * lw[t + 256] + lb[t + 256]);
        yr[t + 512] = f2bs((v2 - mu) * rstd * lw[t + 512] + lb[t + 512]);
        return;
    }
    id -= ROWS;
    const float* W; u16* T; int K, N, nt;
    if (id < 1728)      {            W = W0; T = T0; K = 768; N = 2304; nt = 72; }
    else if (id < 2304) { id -= 1728; W = W1; T = T1; K = 768; N = 768;  nt = 24; }
    else if (id < 2592) { id -= 2304; W = W2; T = T2; K = 768; N = 384;  nt = 12; }
    else                { id -= 2592; W = W3; T = T3; K = 384; N = 768;  nt = 24; }
    int n0 = (id % nt) * 32, k0 = (id / nt) * 32;
    int tx = t & 31, ty = t >> 5;
#pragma unroll
    for (int i = 0; i < 4; i++)
        tile[ty + i * 8][tx] = W[(long)(k0 + ty + i * 8) * N + n0 + tx];
    __syncthreads();
#pragma unroll
    for (int i = 0; i < 4; i++)
        T[(long)(n0 + ty + i * 8) * K + k0 + tx] = f2bs(tile[tx][ty + i * 8]);
}

// ---------------- layernorm, bf16 in -> bf16 out, one block per row ----------------
__global__ __launch_bounds__(256) void lnorm_b(const u16* __restrict__ X,
                                               const float* __restrict__ w,
                                               const float* __restrict__ b,
                                               u16* __restrict__ Y) {
    int row = blockIdx.x;
    const u16* xr = X + (long)row * DIM;
    int t = threadIdx.x;
    float v0 = bs2f(xr[t]), v1 = bs2f(xr[t + 256]), v2 = bs2f(xr[t + 512]);
    float s = v0 + v1 + v2;
    float s2 = v0 * v0 + v1 * v1 + v2 * v2;
    for (int off = 1; off < 64; off <<= 1) {
        s  += __shfl_xor(s,  off, 64);
        s2 += __shfl_xor(s2, off, 64);
    }
    __shared__ float ss[4], ss2[4];
    int wid = t >> 6;
    if ((t & 63) == 0) { ss[wid] = s; ss2[wid] = s2; }
    __syncthreads();
    s  = ss[0] + ss[1] + ss[2] + ss[3];
    s2 = ss2[0] + ss2[1] + ss2[2] + ss2[3];
    float mu = s * (1.0f / DIM);
    float var = s2 * (1.0f / DIM) - mu * mu;
    float rstd = rsqrtf(var + 1e-5f);
    u16* yr = Y + (long)row * DIM;
    yr[t]       = f2bs((v0 - mu) * rstd * w[t]       + b[t]);
    yr[t + 256] = f2bs((v1 - mu) * rstd * w[t + 256] + b[t + 256]);
    yr[t + 512] = f2bs((v2 - mu) * rstd * w[t + 512] + b[t + 512]);
}

// ---------------- bf16 MFMA GEMM, C = A[M,K] @ Bt[N,K]^T, BMxBNx64 tiles ----------------
// 1D grid with XCD-chunked swizzle (T1). Staging via global_load_lds width=16 into
// unpadded stride-64 LDS with XOR swizzle. nblk = N/BN.
// EPI: 0 = bf16 out; 2 = bf16 out + bias + exact GELU;
//      4 = bf16 out + f32 resid (x1 = x + attn@proj, stored bf16);
//      5 = f32 out + bf16 resid + bias (final: out = x1_bf16 + g@fc2 + b).
template <int BM, int BN, int EPI>
__global__ __launch_bounds__(256) void gemm_bt(const u16* __restrict__ A,
                                               const u16* __restrict__ Bt,
                                               int M, int N, int K, int nblk,
                                               u16* __restrict__ Cb,
                                               float* __restrict__ Cf,
                                               const float* __restrict__ resid,
                                               const u16* __restrict__ residb,
                                               const float* __restrict__ bias) {
    constexpr int MB = BM / 32, NB = BN / 32;
    __shared__ u16 As[BM * 64];
    __shared__ u16 Bs[BN * 64];
    int lin = blockIdx.x;
    int cpx = gridDim.x >> 3;                 // grid divisible by 8 at all call sites
    int swz = (lin & 7) * cpx + (lin >> 3);   // XCD-chunked bijection
    int m0 = (swz / nblk) * BM;
    int n0 = (swz % nblk) * BN;
    int t = threadIdx.x;
    int lane = t & 63, w = t >> 6;
    int quad = lane >> 4, l16 = lane & 15;
    int wr = w >> 1, wc = w & 1;
    int lr = lane >> 3, lc = lane & 7;
    int sc = (lc ^ lr) * 8;      // swizzled source chunk offset (u16 units)
    int x7 = l16 & 7;            // row&7 for fragment reads

    f32x4 acc[MB][NB];
#pragma unroll
    for (int mb = 0; mb < MB; mb++)
#pragma unroll
        for (int nb = 0; nb < NB; nb++) acc[mb][nb] = (f32x4){0.f, 0.f, 0.f, 0.f};

    for (int kt = 0; kt < K; kt += 64) {
        __syncthreads();
#pragma unroll
        for (int i = 0; i < BM / 32; i++) {
            int rb = i * 32 + w * 8;
            gld16(&A[(long)(m0 + rb + lr) * K + kt + sc], &As[rb * 64]);
        }
#pragma unroll
        for (int i = 0; i < BN / 32; i++) {
            int rb = i * 32 + w * 8;
            gld16(&Bt[(long)(n0 + rb + lr) * K + kt + sc], &Bs[rb * 64]);
        }
        __syncthreads();
#pragma unroll
        for (int kh = 0; kh < 2; kh++) {
            bf16x8 af[MB], bfr[NB];
#pragma unroll
            for (int mb = 0; mb < MB; mb++)
                af[mb] = *(const bf16x8*)&As[(wr * (BM / 2) + mb * 16 + l16) * 64 +
                                             (((kh * 4 + quad) ^ x7) * 8)];
#pragma unroll
            for (int nb = 0; nb < NB; nb++)
                bfr[nb] = *(const bf16x8*)&Bs[(wc * (BN / 2) + nb * 16 + l16) * 64 +
                                              (((kh * 4 + quad) ^ x7) * 8)];
#pragma unroll
            for (int mb = 0; mb < MB; mb++)
#pragma unroll
                for (int nb = 0; nb < NB; nb++)
                    acc[mb][nb] = __builtin_amdgcn_mfma_f32_16x16x32_bf16(af[mb], bfr[nb], acc[mb][nb], 0, 0, 0);
        }
    }

    int mbase = m0 + wr * (BM / 2), nbase = n0 + wc * (BN / 2);
#pragma unroll
    for (int mb = 0; mb < MB; mb++)
#pragma unroll
        for (int nb = 0; nb < NB; nb++) {
            int r0 = mbase + mb * 16 + quad * 4;
            int c = nbase + nb * 16 + l16;
#pragma unroll
            for (int r = 0; r < 4; r++) {
                float v = acc[mb][nb][r];
                long idx = (long)(r0 + r) * N + c;
                if (EPI == 0) {
                    Cb[idx] = f2bs(v);
                } else if (EPI == 2) {
                    float xg = v + bias[c];
                    Cb[idx] = f2bs(xg * 0.5f * (1.0f + erff(xg * 0.70710678118f)));
                } else if (EPI == 4) {
                    Cb[idx] = f2bs(resid[idx] + v);
                } else {  // EPI == 5
                    Cf[idx] = bs2f(residb[idx]) + v + bias[c];
                }
            }
        }
}

// ---------------- flash attention: QT=128 q-rows/block (8 waves), KT=64 keys/tile ----------------
// Per wave: 16 q-rows; S^T QK^T, in-lane softmax, in-register P.
// PV via 16x16x32 MFMA with PERMUTED contraction index (MFMA sums over k in any order):
// A = concat of two in-lane P quads, B = concat of the two bf16x4 V^T reads.
// K staged via global_load_lds DMA; V via register prefetch + pack into Vs[d][kv] s72.
// Double-buffered, one barrier per tile. defer-max THR=8 (T13). exp2 via raw v_exp_f32.
__global__ __launch_bounds__(512, 6) void attn(const u16* __restrict__ QKV, u16* __restrict__ O) {
    __shared__ u16 Ks[2][64 * 64];    // [buf][kv][chunk-swizzled d]  (DMA-staged)
    __shared__ u16 Vs[2][64 * 72];    // [buf][d][kv], stride 72      (reg-packed)
    int lin = blockIdx.x;
    int cpx = gridDim.x >> 3;                 // gridDim.x divisible by 8
    int l = (lin & 7) * cpx + (lin >> 3);     // XCD-chunked bijection
    int q0 = (l & 7) * 128;                   // SEQ/128 = 8 q-chunks
    int hb = l >> 3;
    int h = hb % NHEAD;
    int b = hb / NHEAD;
    int t = threadIdx.x;
    int lane = t & 63, w = t >> 6;            // w in 0..7
    int quad = lane >> 4, l16 = lane & 15;
    int x7 = l16 & 7;

    const long rs = 3 * DIM;  // 2304
    const u16* base = QKV + (long)b * SEQ * rs;

    // Q fragments: wave w owns rows q0 + w*16 .. +15
    bf16x8 qf0, qf1;
    {
        int qrow = q0 + w * 16 + l16;
        qf0 = *(const bf16x8*)&base[(long)qrow * rs + h * 64 + quad * 8];
        qf1 = *(const bf16x8*)&base[(long)qrow * rs + h * 64 + 32 + quad * 8];
    }

    f32x4 o[4];
#pragma unroll
    for (int dt = 0; dt < 4; dt++) o[dt] = (f32x4){0.f, 0.f, 0.f, 0.f};
    float m_run = -1e30f;
    float l_run = 0.f;
    const float L2E8 = 11.54156032f;  // 8 * log2(e)

    // ---- staging sources ----
    // K DMA: wave w stages rows w*8..+7 in ONE gld16 (8 lanes/row, 16B chunks,
    //        source chunk pre-swizzled (lc ^ lr); row&7 == lr since w*8 is 8-aligned).
    int lr = lane >> 3, lc = lane & 7;
    int sc = (lc ^ lr) * 8;
    const u16* kA = &base[(long)(w * 8 + lr) * rs + DIM + h * 64 + sc];
    // V regs: thread t loads V rows 2vc,2vc+1 (vc=t&31), d-group vo*4..+3 (vo=t>>5, 0..15)
    int vc = t & 31, vo = t >> 5;
    const u16* vptr = &base[(long)(2 * vc) * rs + 2 * DIM + h * 64 + vo * 4];
    const long kstep = (long)64 * rs;

    bf16x4 vp0, vp1;
    // ---- prologue: tile 0 ----
    gld16(kA, &Ks[0][(w * 8) * 64]);
    kA += kstep;
    vp0 = *(const bf16x4*)&vptr[0];
    vp1 = *(const bf16x4*)&vptr[rs];
    vptr += kstep;
#pragma unroll
    for (int j = 0; j < 4; j++) {
        u32 pk = (u32)(u16)vp0[j] | ((u32)(u16)vp1[j] << 16);
        *(u32*)&Vs[0][(vo * 4 + j) * 72 + 2 * vc] = pk;
    }
    // V regs for tile 1
    vp0 = *(const bf16x4*)&vptr[0];
    vp1 = *(const bf16x4*)&vptr[rs];
    vptr += kstep;
    __syncthreads();   // drains K DMA (vmcnt) + V ds_writes (lgkm) before reads

    for (int it = 0; it < SEQ / 64; it++) {
        int cur = it & 1;
        if (it < SEQ / 64 - 1) {
            int nb = cur ^ 1;
            // K DMA for tile it+1 (buf nb fully read in iter it-1; barrier passed)
            gld16(kA, &Ks[nb][(w * 8) * 64]);
            kA += kstep;
            // V write for tile it+1 (regs loaded one iteration ago)
#pragma unroll
            for (int j = 0; j < 4; j++) {
                u32 pk = (u32)(u16)vp0[j] | ((u32)(u16)vp1[j] << 16);
                *(u32*)&Vs[nb][(vo * 4 + j) * 72 + 2 * vc] = pk;
            }
            if (it < SEQ / 64 - 2) {
                vp0 = *(const bf16x4*)&vptr[0];
                vp1 = *(const bf16x4*)&vptr[rs];
                vptr += kstep;
            }
        }

        // ---- QK^T from buf[cur]: lane (quad,l16) gets s[jb][r] = S[q=l16][kv=jb*16+quad*4+r]
        f32x4 s[4];
#pragma unroll
        for (int jb = 0; jb < 4; jb++) {
            int row = jb * 16 + l16;
            bf16x8 kf0 = *(const bf16x8*)&Ks[cur][row * 64 + ((quad ^ x7) * 8)];
            bf16x8 kf1 = *(const bf16x8*)&Ks[cur][row * 64 + (((4 + quad) ^ x7) * 8)];
            f32x4 z = (f32x4){0.f, 0.f, 0.f, 0.f};
            z = __builtin_amdgcn_mfma_f32_16x16x32_bf16(kf0, qf0, z, 0, 0, 0);
            z = __builtin_amdgcn_mfma_f32_16x16x32_bf16(kf1, qf1, z, 0, 0, 0);
            s[jb] = z;
        }

        // ---- softmax (vectorized)
        f32x4 mx = __builtin_elementwise_max(__builtin_elementwise_max(s[0], s[1]),
                                             __builtin_elementwise_max(s[2], s[3]));
        float m1 = fmaxf(fmaxf(mx[0], mx[1]), fmaxf(mx[2], mx[3]));
        m1 = fmaxf(m1, __shfl_xor(m1, 16, 64));
        m1 = fmaxf(m1, __shfl_xor(m1, 32, 64));

        // defer-max (T13, THR=8): skip O/l rescale unless some row's max grew by >8
        // (P then bounded by e^8 ~ 2981 -- safe in f32 sums / bf16 P).
        float mn = m_run;
        int resc = __any(m1 > mn + 8.0f);
        if (resc) mn = fmaxf(mn, m1);
        float mn8 = mn * L2E8;
        f32x4 cmul = {L2E8, L2E8, L2E8, L2E8};
        f32x4 cadd = {-mn8, -mn8, -mn8, -mn8};
#pragma unroll
        for (int jb = 0; jb < 4; jb++) {
            f32x4 e = s[jb] * cmul + cadd;
            e[0] = fexp2(e[0]); e[1] = fexp2(e[1]);
            e[2] = fexp2(e[2]); e[3] = fexp2(e[3]);
            s[jb] = e;
        }
        f32x4 sv = (s[0] + s[1]) + (s[2] + s[3]);
        float rsum = (sv[0] + sv[1]) + (sv[2] + sv[3]);
        rsum += __shfl_xor(rsum, 16, 64);
        rsum += __shfl_xor(rsum, 32, 64);

        if (resc) {
            float alpha = fexp2((m_run - mn) * L2E8);
            m_run = mn;
            float a0 = __shfl(alpha, quad * 4 + 0, 16);
            float a1 = __shfl(alpha, quad * 4 + 1, 16);
            float a2 = __shfl(alpha, quad * 4 + 2, 16);
            float a3 = __shfl(alpha, quad * 4 + 3, 16);
#pragma unroll
            for (int dt = 0; dt < 4; dt++) {
                o[dt][0] *= a0; o[dt][1] *= a1;
                o[dt][2] *= a2; o[dt][3] *= a3;
            }
            l_run = l_run * alpha + rsum;
        } else {
            l_run += rsum;
        }

        // ---- PV: 16x16x32 with permuted k. A = concat(P[jb0],P[jb1]) in-lane;
        //          B = concat of the two bf16x4 V^T reads (same addresses as K=16 version).
#pragma unroll
        for (int jp = 0; jp < 2; jp++) {
            int jb0 = 2 * jp, jb1 = 2 * jp + 1;
            union { u32 u[4]; bf16x8 v; } pa;
            pa.u[0] = packbf2(s[jb0][0], s[jb0][1]);
            pa.u[1] = packbf2(s[jb0][2], s[jb0][3]);
            pa.u[2] = packbf2(s[jb1][0], s[jb1][1]);
            pa.u[3] = packbf2(s[jb1][2], s[jb1][3]);
#pragma unroll
            for (int dt = 0; dt < 4; dt++) {
                union { bf16x4 h[2]; bf16x8 v; } vb;
                vb.h[0] = *(const bf16x4*)&Vs[cur][(dt * 16 + l16) * 72 + jb0 * 16 + quad * 4];
                vb.h[1] = *(const bf16x4*)&Vs[cur][(dt * 16 + l16) * 72 + jb1 * 16 + quad * 4];
                o[dt] = __builtin_amdgcn_mfma_f32_16x16x32_bf16(pa.v, vb.v, o[dt], 0, 0, 0);
            }
        }

        if (it < SEQ / 64 - 1) __syncthreads();   // protects buf[cur] overwrite next iter
    }

    // epilogue: rows quad*4+r, cols dt*16+l16. 1/l via v_rcp_f32 (l >= 1, 1-ulp ok for bf16)
    {
        float l0 = __builtin_amdgcn_rcpf(__shfl(l_run, quad * 4 + 0, 16));
        float l1 = __builtin_amdgcn_rcpf(__shfl(l_run, quad * 4 + 1, 16));
        float l2 = __builtin_amdgcn_rcpf(__shfl(l_run, quad * 4 + 2, 16));
        float l3 = __builtin_amdgcn_rcpf(__shfl(l_run, quad * 4 + 3, 16));
        u16* orow = O + ((long)(b * SEQ + q0 + w * 16)) * DIM + h * 64;
#pragma unroll
        for (int dt = 0; dt < 4; dt++) {
            u32 p01 = packbf2(o[dt][0] * l0, o[dt][1] * l1);
            u32 p23 = packbf2(o[dt][2] * l2, o[dt][3] * l3);
            int cidx = dt * 16 + l16;
            orow[(long)(quad * 4 + 0) * DIM + cidx] = (u16)p01;
            orow[(long)(quad * 4 + 1) * DIM + cidx] = (u16)(p01 >> 16);
            orow[(long)(quad * 4 + 2) * DIM + cidx] = (u16)p23;
            orow[(long)(quad * 4 + 3) * DIM + cidx] = (u16)(p23 >> 16);
        }
    }
}

extern "C" void kernel_launch(void* const* d_in, const int* in_sizes, int n_in,
                              void* d_out, int out_size, void* d_ws, size_t ws_size,
                              hipStream_t stream) {
    const float* x     = (const float*)d_in[0];
    const float* ln1w  = (const float*)d_in[1];
    const float* ln1b  = (const float*)d_in[2];
    const float* ln2w  = (const float*)d_in[3];
    const float* ln2b  = (const float*)d_in[4];
    const float* wqkv  = (const float*)d_in[5];
    const float* wproj = (const float*)d_in[6];
    const float* wfc1  = (const float*)d_in[7];
    const float* bfc1  = (const float*)d_in[8];
    const float* wfc2  = (const float*)d_in[9];
    const float* bfc2  = (const float*)d_in[10];
    float* out = (float*)d_out;

    char* ws = (char*)d_ws;
    size_t off = 0;
    auto alloc = [&](size_t bytes) {
        void* p = ws + off;
        off = (off + bytes + 255) & ~(size_t)255;
        return p;
    };
    u16* wt_qkv  = (u16*)alloc((size_t)3 * DIM * DIM * 2);
    u16* wt_proj = (u16*)alloc((size_t)DIM * DIM * 2);
    u16* wt_fc1  = (u16*)alloc((size_t)HIDDEN * DIM * 2);
    u16* wt_fc2  = (u16*)alloc((size_t)DIM * HIDDEN * 2);
    u16* hbuf    = (u16*)alloc((size_t)ROWS * DIM * 2);      // ln1 out -> attn out -> ln2 out
    u16* gbuf    = (u16*)alloc((size_t)ROWS * HIDDEN * 2);   // gelu out
    u16* hbuf2   = (u16*)alloc((size_t)ROWS * DIM * 2);      // x1 residual stream (bf16)
    size_t qkv_bytes = (size_t)ROWS * 3 * DIM * 2;           // 37.75 MB
    u16* qkvfull = (off + qkv_bytes + 1024 <= ws_size) ? (u16*)alloc(qkv_bytes) : nullptr;

    // 1. prep: ln1 (8192 blocks) + 4x weight transpose (2880 blocks), single launch
    prep<<<ROWS + 2880, 256, 0, stream>>>(x, ln1w, ln1b, hbuf,
                                          wqkv, wt_qkv, wproj, wt_proj,
                                          wfc1, wt_fc1, wfc2, wt_fc2);

    // 2. qkv + attention  (1D grids, XCD-chunk swizzled; all divisible by 8)
    if (qkvfull) {
        gemm_bt<128, 128, 0><<<(3 * DIM / 128) * (ROWS / 128), 256, 0, stream>>>(
            hbuf, wt_qkv, ROWS, 3 * DIM, DIM, 3 * DIM / 128, qkvfull, nullptr, nullptr, nullptr, nullptr);
        attn<<<(SEQ / 128) * NHEAD * BATCH, 512, 0, stream>>>(qkvfull, hbuf);
    } else {
        u16* qd = (u16*)d_out;
        for (int c = 0; c < ROWS / CHUNKR; c++) {
            const u16* hA = hbuf + (size_t)c * CHUNKR * DIM;
            gemm_bt<128, 128, 0><<<(3 * DIM / 128) * (CHUNKR / 128), 256, 0, stream>>>(
                hA, wt_qkv, CHUNKR, 3 * DIM, DIM, 3 * DIM / 128, qd, nullptr, nullptr, nullptr, nullptr);
            attn<<<(SEQ / 128) * NHEAD * CHUNKB, 512, 0, stream>>>(
                qd, hbuf + (size_t)c * CHUNKR * DIM);
        }
    }

    // 3. x1 = bf16(x + attn_out @ w_proj)  (bf16 residual stream into hbuf2)
    gemm_bt<128, 64, 4><<<(DIM / 64) * (ROWS / 128), 256, 0, stream>>>(
        hbuf, wt_proj, ROWS, DIM, DIM, DIM / 64, hbuf2, nullptr, x, nullptr, nullptr);

    // 4. ln2 (bf16 in -> bf16 out)
    lnorm_b<<<ROWS, 256, 0, stream>>>(hbuf2, ln2w, ln2b, hbuf);

    // 5. g = gelu(hbuf @ w_fc1 + b_fc1)
    gemm_bt<64, 64, 2><<<(HIDDEN / 64) * (ROWS / 64), 256, 0, stream>>>(
        hbuf, wt_fc1, ROWS, HIDDEN, DIM, HIDDEN / 64, gbuf, nullptr, nullptr, nullptr, bfc1);

    // 6. out = x1 + g @ w_fc2 + b_fc2  (f32 final; resid read bf16)
    gemm_bt<128, 64, 5><<<(DIM / 64) * (ROWS / 128), 256, 0, stream>>>(
        gbuf, wt_fc2, ROWS, DIM, HIDDEN, DIM / 64, nullptr, out, nullptr, hbuf2, bfc2);
}